// Round 10
// baseline (292.730 us; speedup 1.0000x reference)
//
#include <hip/hip_runtime.h>
#include <hip/hip_bf16.h>
#include <cstdint>
#include <math.h>

// Problem constants
#define SEQ 1024
#define DIM 2560
#define HD 128
#define NH 20
#define NKV 5
#define QKV_OUT 3840
#define GS 128

typedef __bf16 bf16;
typedef __bf16 bf16x4 __attribute__((ext_vector_type(4)));
typedef __bf16 bf16x8 __attribute__((ext_vector_type(8)));
typedef float f32x4 __attribute__((ext_vector_type(4)));

// ---------------------------------------------------------------------------
// 1) per-token activation quant (templated input dtype)
// ---------------------------------------------------------------------------
template <typename T>
__global__ __launch_bounds__(256) void quant_kernel(
    const T* __restrict__ x, bf16* __restrict__ act,
    float* __restrict__ rs, int cols) {
  const int row = blockIdx.x;
  const int tid = threadIdx.x;
  const T* xr = x + (size_t)row * cols;
  float m = 0.f;
  for (int i = tid; i < cols; i += 256) m = fmaxf(m, fabsf((float)xr[i]));
  for (int off = 32; off; off >>= 1) m = fmaxf(m, __shfl_xor(m, off));
  __shared__ float red[4];
  __shared__ float s_bc;
  if ((tid & 63) == 0) red[tid >> 6] = m;
  __syncthreads();
  if (tid == 0) {
    float mm = fmaxf(fmaxf(red[0], red[1]), fmaxf(red[2], red[3]));
    mm = fmaxf(mm, 1e-5f);
    s_bc = 127.f / mm;
    rs[row] = mm / 127.f;
  }
  __syncthreads();
  const float s = s_bc;
  bf16* ar = act + (size_t)row * cols;
  for (int i = tid; i < cols; i += 256) {
    float q = rintf((float)xr[i] * s);
    q = fminf(fmaxf(q, -128.f), 127.f);
    ar[i] = (bf16)q;
  }
}

// ---------------------------------------------------------------------------
// 2) fused dequant GEMM: C[m,n] = (sum_k A[m,k] * bf16(W[n,k]*WS[n,k/GS])) * rs[m]
//    A bf16 [M,K]; W fp32 [N,K]; split-K via blockIdx.z (Kh = K/gridDim.z).
//    Tile 64(M) x BN(N), BK=64. A staged via global_load_lds (XOR-swizzled on
//    the global side); B loaded fp32 -> converted in regs -> ds_write_b128
//    into swizzled LDS. Double-buffered, ONE barrier per K-tile.
// ---------------------------------------------------------------------------
__device__ __forceinline__ void gload_lds16(const bf16* g, bf16* l) {
  __builtin_amdgcn_global_load_lds(
      (const __attribute__((address_space(1))) void*)g,
      (__attribute__((address_space(3))) void*)l, 16, 0, 0);
}

template <int BN>
__global__ __launch_bounds__(256) void gemm_fused(
    const bf16* __restrict__ A, const float* __restrict__ W,
    const float* __restrict__ WS, const float* __restrict__ rs,
    float* __restrict__ C, int N, int K, int Kh, size_t part_stride) {
  constexpr int NW = BN / 32;            // N-frags per wave
  constexpr int NPASS = BN * 8 / 256;    // B granules per thread
  __shared__ bf16 As[2][64 * 64];
  __shared__ bf16 Bs[2][BN * 64];
  const int tid = threadIdx.x;
  const int w = tid >> 6, l = tid & 63;
  const int row0 = blockIdx.y * 64;
  const int col0 = blockIdx.x * BN;
  const int z = blockIdx.z;
  const int wm = (w >> 1) * 32, wn = (w & 1) * (BN / 2);
  const int lcol = l & 15, quad = l >> 4;
  const int sr = l >> 3, sg = l & 7;
  const bf16* Ag = A + (size_t)row0 * K + (size_t)z * Kh;
  const int ksc = K / GS;

  // B granule assignment: granule gI = p*256+tid -> row gI>>3, j = gI&7
  int brow[NPASS], bj[NPASS];
#pragma unroll
  for (int p = 0; p < NPASS; ++p) {
    int gI = p * 256 + tid;
    brow[p] = gI >> 3;
    bj[p] = gI & 7;
  }

  float4 bl[NPASS][2];
  float bsc[NPASS];
  f32x4 acc[2][NW] = {};

#define STAGE_A(buf, k0)                                                       \
  {                                                                            \
    _Pragma("unroll") for (int i = 0; i < 2; ++i) {                            \
      int rb = w * 16 + i * 8;                                                 \
      int r = rb + sr;                                                         \
      gload_lds16(Ag + (size_t)r * K + (k0) + ((sg ^ (r & 7)) * 8),            \
                  &As[buf][rb * 64]);                                          \
    }                                                                          \
  }
#define LOAD_B(k0)                                                             \
  {                                                                            \
    int grp = (z * Kh + (k0)) / GS;                                            \
    _Pragma("unroll") for (int p = 0; p < NPASS; ++p) {                        \
      const float* wp =                                                        \
          W + (size_t)(col0 + brow[p]) * K + (size_t)z * Kh + (k0) + bj[p] * 8;\
      bl[p][0] = *(const float4*)wp;                                           \
      bl[p][1] = *(const float4*)(wp + 4);                                     \
      bsc[p] = WS[(size_t)(col0 + brow[p]) * ksc + grp];                       \
    }                                                                          \
  }
#define WRITE_B(buf)                                                           \
  {                                                                            \
    _Pragma("unroll") for (int p = 0; p < NPASS; ++p) {                        \
      float sc = bsc[p];                                                       \
      bf16x8 o;                                                                \
      o[0] = (bf16)(bl[p][0].x * sc); o[1] = (bf16)(bl[p][0].y * sc);          \
      o[2] = (bf16)(bl[p][0].z * sc); o[3] = (bf16)(bl[p][0].w * sc);          \
      o[4] = (bf16)(bl[p][1].x * sc); o[5] = (bf16)(bl[p][1].y * sc);          \
      o[6] = (bf16)(bl[p][1].z * sc); o[7] = (bf16)(bl[p][1].w * sc);          \
      *(bf16x8*)&Bs[buf][brow[p] * 64 + ((bj[p] ^ (brow[p] & 7)) * 8)] = o;    \
    }                                                                          \
  }

  // prologue: stage tile 0 into buf 0
  STAGE_A(0, 0)
  LOAD_B(0)
  WRITE_B(0)
  __syncthreads();

  int buf = 0;
  for (int k0 = 0; k0 < Kh; k0 += 64) {
    const bool has_next = (k0 + 64) < Kh;
    if (has_next) {
      STAGE_A(buf ^ 1, k0 + 64)
      LOAD_B(k0 + 64)
    }
    // ---- compute tile from buf ----
#pragma unroll
    for (int ks = 0; ks < 2; ++ks) {
      bf16x8 af[2], bff[NW];
#pragma unroll
      for (int mi = 0; mi < 2; ++mi) {
        int R = wm + mi * 16 + lcol;
        af[mi] = *(const bf16x8*)(&As[buf][R * 64 + (((ks * 4 + quad) ^ (R & 7)) * 8)]);
      }
#pragma unroll
      for (int ni = 0; ni < NW; ++ni) {
        int R = wn + ni * 16 + lcol;
        bff[ni] = *(const bf16x8*)(&Bs[buf][R * 64 + (((ks * 4 + quad) ^ (R & 7)) * 8)]);
      }
#pragma unroll
      for (int mi = 0; mi < 2; ++mi)
#pragma unroll
        for (int ni = 0; ni < NW; ++ni)
          acc[mi][ni] = __builtin_amdgcn_mfma_f32_16x16x32_bf16(
              af[mi], bff[ni], acc[mi][ni], 0, 0, 0);
    }
    if (has_next) WRITE_B(buf ^ 1)
    __syncthreads();   // drains glds (vmcnt) + ds_writes; flips buffer safely
    buf ^= 1;
  }
#undef STAGE_A
#undef LOAD_B
#undef WRITE_B

  float* Cp = C + (size_t)z * part_stride;
#pragma unroll
  for (int mi = 0; mi < 2; ++mi) {
#pragma unroll
    for (int ni = 0; ni < NW; ++ni) {
      int col = col0 + wn + ni * 16 + lcol;
#pragma unroll
      for (int r = 0; r < 4; ++r) {
        int row = row0 + wm + mi * 16 + quad * 4 + r;
        Cp[(size_t)row * N + col] = acc[mi][ni][r] * rs[row];
      }
    }
  }
}

// ---------------------------------------------------------------------------
// 4a) q/k postprocess: sum split-K partials + rmsnorm + rope; bf16 out.
// ---------------------------------------------------------------------------
__global__ void qk_post(const float* __restrict__ qkvA, const float* __restrict__ qkvB,
                        const float* __restrict__ qw, const float* __restrict__ kw,
                        bf16* __restrict__ Qo, bf16* __restrict__ Ko) {
  const int t = blockIdx.x, h = blockIdx.y, i = threadIdx.x;
  const size_t off = (h < NH)
      ? (size_t)t * QKV_OUT + h * HD
      : (size_t)t * QKV_OUT + 2560 + (h - NH) * HD;
  const float* s1 = qkvA + off;
  const float* s2 = qkvB + off;
  float x0 = s1[2 * i] + s2[2 * i];
  float x1 = s1[2 * i + 1] + s2[2 * i + 1];
  float ss = x0 * x0 + x1 * x1;
  for (int off2 = 1; off2 < 64; off2 <<= 1) ss += __shfl_xor(ss, off2);
  float r = rsqrtf(ss * (1.f / 128.f) + 1e-5f);
  const float* wv = (h < NH) ? qw : kw;
  float y0 = x0 * r * wv[2 * i];
  float y1 = x1 * r * wv[2 * i + 1];
  float inv_freq = powf(500000.f, -(float)(2 * i) * (1.f / 128.f));
  float ang = (float)t * inv_freq;
  float sn, cs;
  sincosf(ang, &sn, &cs);
  float o0 = y0 * cs - y1 * sn;
  float o1 = y0 * sn + y1 * cs;
  if (h < NH) {
    bf16* dst = Qo + ((size_t)t * NH + h) * HD + 2 * i;
    dst[0] = (bf16)o0; dst[1] = (bf16)o1;
  } else {
    bf16* dst = Ko + ((size_t)(h - NH) * SEQ + t) * HD + 2 * i;
    dst[0] = (bf16)o0; dst[1] = (bf16)o1;
  }
}

// ---------------------------------------------------------------------------
// 4b) V transpose: sum partials, fp32 [t][3200+g*128+d] -> Vt bf16 [g][d][t]
// ---------------------------------------------------------------------------
__global__ __launch_bounds__(256) void v_post(const float* __restrict__ qkvA,
                                              const float* __restrict__ qkvB,
                                              bf16* __restrict__ Vt) {
  const int t0 = blockIdx.x * 64, g = blockIdx.y;
  const int tid = threadIdx.x;
  __shared__ bf16 Ls[64 * 137];
  {
    const int tl = tid >> 4;
    const int d0 = (tid & 15) * 8;
#pragma unroll
    for (int pass = 0; pass < 4; ++pass) {
      int t = pass * 16 + tl;
      size_t off = (size_t)(t0 + t) * QKV_OUT + 3200 + g * HD + d0;
      float4 a = *(const float4*)(qkvA + off);
      float4 b = *(const float4*)(qkvA + off + 4);
      float4 a2 = *(const float4*)(qkvB + off);
      float4 b2 = *(const float4*)(qkvB + off + 4);
      bf16* dst = Ls + t * 137 + d0;
      dst[0] = (bf16)(a.x + a2.x); dst[1] = (bf16)(a.y + a2.y);
      dst[2] = (bf16)(a.z + a2.z); dst[3] = (bf16)(a.w + a2.w);
      dst[4] = (bf16)(b.x + b2.x); dst[5] = (bf16)(b.y + b2.y);
      dst[6] = (bf16)(b.z + b2.z); dst[7] = (bf16)(b.w + b2.w);
    }
  }
  __syncthreads();
  {
    const int dl = tid >> 3;
    const int tl0 = (tid & 7) * 8;
#pragma unroll
    for (int pass = 0; pass < 4; ++pass) {
      int d = pass * 32 + dl;
      bf16x8 v;
#pragma unroll
      for (int j = 0; j < 8; ++j) v[j] = Ls[(tl0 + j) * 137 + d];
      *(bf16x8*)(Vt + ((size_t)g * HD + d) * SEQ + t0 + tl0) = v;
    }
  }
}

// ---------------------------------------------------------------------------
// 5) MFMA GQA causal flash attention (round-9 structure, unchanged).
// ---------------------------------------------------------------------------
__global__ __launch_bounds__(256) void attn_mfma(
    const bf16* __restrict__ Qb, const bf16* __restrict__ Kb,
    const bf16* __restrict__ Vt, bf16* __restrict__ O) {
  const int qb = 31 - (int)blockIdx.x;     // long blocks first
  const int hp = blockIdx.y;
  const int tid = threadIdx.x;
  const int wave = tid >> 6, lane = tid & 63;
  const int H = (hp >> 1) * 4 + (hp & 1) * 2 + (wave >> 1);
  const int g = H >> 2;
  const int qcol = lane & 15, quad = lane >> 4;
  const int q_tok = qb * 32 + (wave & 1) * 16 + qcol;
  const float scale = 0.08838834764831843f;

  __shared__ bf16 Ks[2][64 * 128];
  __shared__ bf16 Vs[2][128 * 64];

  const bf16* kbase = Kb + (size_t)g * SEQ * HD;
  const bf16* vbase = Vt + (size_t)g * HD * SEQ;

  bf16x8 qf[4];
  {
    const bf16* qp = Qb + ((size_t)q_tok * NH + H) * HD + quad * 8;
#pragma unroll
    for (int kc = 0; kc < 4; ++kc) qf[kc] = *(const bf16x8*)(qp + kc * 32);
  }

  float m_i = -1e30f, l_i = 0.f;
  f32x4 o_acc[8] = {};
  const int kt_max = (qb * 32 + 31) >> 6;

  const int k_r = lane >> 4, k_g = lane & 15;
  const int v_r = lane >> 3, v_g = lane & 7;

#define STAGE(buf, key0)                                                       \
  {                                                                            \
    _Pragma("unroll") for (int p = 0; p < 4; ++p) {                            \
      int r0 = wave * 16 + p * 4;                                              \
      int r = r0 + k_r;                                                        \
      gload_lds16(kbase + (size_t)((key0) + r) * HD + ((k_g ^ (r & 15)) * 8),  \
                  &Ks[buf][r0 * 128]);                                         \
    }                                                                          \
    _Pragma("unroll") for (int p = 0; p < 4; ++p) {                            \
      int r0 = wave * 32 + p * 8;                                              \
      int r = r0 + v_r;                                                        \
      gload_lds16(vbase + (size_t)r * SEQ + (key0) + ((v_g ^ (r & 7)) * 8),    \
                  &Vs[buf][r0 * 64]);                                          \
    }                                                                          \
  }

  STAGE(0, 0)

  for (int kt = 0; kt <= kt_max; ++kt) {
    const int key0 = kt * 64;
    __syncthreads();
    if (kt < kt_max) STAGE((kt + 1) & 1, key0 + 64)
    const bf16* Kt = Ks[kt & 1];
    const bf16* Vtile = Vs[kt & 1];

    f32x4 s[4];
#pragma unroll
    for (int mg = 0; mg < 4; ++mg) {
      const int R = mg * 16 + qcol;
      const bf16* krow = Kt + R * 128;
      f32x4 acc = {0.f, 0.f, 0.f, 0.f};
#pragma unroll
      for (int kc = 0; kc < 4; ++kc) {
        int j = kc * 4 + quad;
        bf16x8 kf = *(const bf16x8*)(krow + ((j ^ (R & 15)) * 8));
        acc = __builtin_amdgcn_mfma_f32_16x16x32_bf16(kf, qf[kc], acc, 0, 0, 0);
      }
      s[mg] = acc;
    }

    float mt = -1e30f;
#pragma unroll
    for (int mg = 0; mg < 4; ++mg)
#pragma unroll
      for (int r = 0; r < 4; ++r) {
        int key = key0 + mg * 16 + quad * 4 + r;
        float v = (key <= q_tok) ? s[mg][r] * scale : -1e30f;
        s[mg][r] = v;
        mt = fmaxf(mt, v);
      }
    mt = fmaxf(mt, __shfl_xor(mt, 16));
    mt = fmaxf(mt, __shfl_xor(mt, 32));
    float mnew = fmaxf(m_i, mt);
    float alpha = __expf(m_i - mnew);
    float ps = 0.f;
#pragma unroll
    for (int mg = 0; mg < 4; ++mg)
#pragma unroll
      for (int r = 0; r < 4; ++r) {
        float pv = __expf(s[mg][r] - mnew);
        s[mg][r] = pv;
        ps += pv;
      }
    ps += __shfl_xor(ps, 16);
    ps += __shfl_xor(ps, 32);
    l_i = l_i * alpha + ps;
    m_i = mnew;
#pragma unroll
    for (int mg2 = 0; mg2 < 8; ++mg2)
#pragma unroll
      for (int r = 0; r < 4; ++r) o_acc[mg2][r] *= alpha;

    bf16x8 pb[2];
#pragma unroll
    for (int c = 0; c < 2; ++c)
#pragma unroll
      for (int j = 0; j < 8; ++j)
        pb[c][j] = (bf16)s[c * 2 + (j >> 2)][j & 3];

#pragma unroll
    for (int mg2 = 0; mg2 < 8; ++mg2) {
      const int R = mg2 * 16 + qcol;
      const bf16* vrow = Vtile + R * 64;
      f32x4 acc = o_acc[mg2];
#pragma unroll
      for (int c = 0; c < 2; ++c) {
        int g8a = c * 8 + quad;
        int g8b = c * 8 + 4 + quad;
        bf16x4 v0 = *(const bf16x4*)(vrow + ((g8a >> 1) ^ (R & 7)) * 8 + (g8a & 1) * 4);
        bf16x4 v1 = *(const bf16x4*)(vrow + ((g8b >> 1) ^ (R & 7)) * 8 + (g8b & 1) * 4);
        bf16x8 vfr;
#pragma unroll
        for (int j = 0; j < 4; ++j) { vfr[j] = v0[j]; vfr[j + 4] = v1[j]; }
        acc = __builtin_amdgcn_mfma_f32_16x16x32_bf16(vfr, pb[c], acc, 0, 0, 0);
      }
      o_acc[mg2] = acc;
    }
  }
#undef STAGE

  const float inv = 1.f / l_i;
  bf16* op = O + (size_t)q_tok * DIM + H * HD + quad * 4;
#pragma unroll
  for (int mg2 = 0; mg2 < 8; ++mg2) {
    bf16x4 vv;
    vv[0] = (bf16)(o_acc[mg2][0] * inv);
    vv[1] = (bf16)(o_acc[mg2][1] * inv);
    vv[2] = (bf16)(o_acc[mg2][2] * inv);
    vv[3] = (bf16)(o_acc[mg2][3] * inv);
    *(bf16x4*)(op + mg2 * 16) = vv;
  }
}

// ---------------------------------------------------------------------------
extern "C" void kernel_launch(void* const* d_in, const int* in_sizes, int n_in,
                              void* d_out, int out_size, void* d_ws, size_t ws_size,
                              hipStream_t stream) {
  const float* x      = (const float*)d_in[0];
  const float* w_qkv  = (const float*)d_in[1];
  const float* ws_qkv = (const float*)d_in[2];
  const float* w_o    = (const float*)d_in[3];
  const float* ws_o   = (const float*)d_in[4];
  const float* qnw    = (const float*)d_in[5];
  const float* knw    = (const float*)d_in[6];
  float* out = (float*)d_out;

  char* p = (char*)d_ws;
  bf16*  act1 = (bf16*)p;  p += (size_t)SEQ * DIM * 2;
  float* rs1  = (float*)p; p += 4096;
  float* qkvA = (float*)p; p += (size_t)SEQ * QKV_OUT * 4;
  float* qkvB = (float*)p; p += (size_t)SEQ * QKV_OUT * 4;
  bf16*  Qb   = (bf16*)p;  p += (size_t)SEQ * NH * HD * 2;
  bf16*  Kb   = (bf16*)p;  p += (size_t)NKV * SEQ * HD * 2;
  bf16*  Vt   = (bf16*)p;  p += (size_t)NKV * HD * SEQ * 2;
  bf16*  attn = (bf16*)p;  p += (size_t)SEQ * DIM * 2;
  bf16*  act2 = (bf16*)p;  p += (size_t)SEQ * DIM * 2;
  float* rs2  = (float*)p; p += 4096;

  quant_kernel<float><<<SEQ, 256, 0, stream>>>(x, act1, rs1, DIM);
  // QKV GEMM: fused dequant, split-K x2 -> qkvA/qkvB partials
  gemm_fused<128><<<dim3(QKV_OUT / 128, SEQ / 64, 2), 256, 0, stream>>>(
      act1, w_qkv, ws_qkv, rs1, qkvA, QKV_OUT, DIM, DIM / 2, (size_t)SEQ * QKV_OUT);
  qk_post<<<dim3(SEQ, 25), 64, 0, stream>>>(qkvA, qkvB, qnw, knw, Qb, Kb);
  v_post<<<dim3(SEQ / 64, NKV), 256, 0, stream>>>(qkvA, qkvB, Vt);
  attn_mfma<<<dim3(32, 10), 256, 0, stream>>>(Qb, Kb, Vt, attn);
  quant_kernel<bf16><<<SEQ, 256, 0, stream>>>(attn, act2, rs2, DIM);
  // O-projection GEMM: fused dequant, full K, writes fp32 d_out directly
  gemm_fused<64><<<dim3(DIM / 64, SEQ / 64, 1), 256, 0, stream>>>(
      act2, w_o, ws_o, rs2, out, DIM, DIM, DIM, 0);
}

// Round 11
// 278.250 us; speedup vs baseline: 1.0520x; 1.0520x over previous
//
#include <hip/hip_runtime.h>
#include <hip/hip_bf16.h>
#include <cstdint>
#include <math.h>

// Problem constants
#define SEQ 1024
#define DIM 2560
#define HD 128
#define NH 20
#define NKV 5
#define QKV_OUT 3840
#define GS 128

typedef __bf16 bf16;
typedef __bf16 bf16x4 __attribute__((ext_vector_type(4)));
typedef __bf16 bf16x8 __attribute__((ext_vector_type(8)));
typedef float f32x4 __attribute__((ext_vector_type(4)));

// ---------------------------------------------------------------------------
// 1) per-token activation quant (templated input dtype)
// ---------------------------------------------------------------------------
template <typename T>
__global__ __launch_bounds__(256) void quant_kernel(
    const T* __restrict__ x, bf16* __restrict__ act,
    float* __restrict__ rs, int cols) {
  const int row = blockIdx.x;
  const int tid = threadIdx.x;
  const T* xr = x + (size_t)row * cols;
  float m = 0.f;
  for (int i = tid; i < cols; i += 256) m = fmaxf(m, fabsf((float)xr[i]));
  for (int off = 32; off; off >>= 1) m = fmaxf(m, __shfl_xor(m, off));
  __shared__ float red[4];
  __shared__ float s_bc;
  if ((tid & 63) == 0) red[tid >> 6] = m;
  __syncthreads();
  if (tid == 0) {
    float mm = fmaxf(fmaxf(red[0], red[1]), fmaxf(red[2], red[3]));
    mm = fmaxf(mm, 1e-5f);
    s_bc = 127.f / mm;
    rs[row] = mm / 127.f;
  }
  __syncthreads();
  const float s = s_bc;
  bf16* ar = act + (size_t)row * cols;
  for (int i = tid; i < cols; i += 256) {
    float q = rintf((float)xr[i] * s);
    q = fminf(fmaxf(q, -128.f), 127.f);
    ar[i] = (bf16)q;
  }
}

// ---------------------------------------------------------------------------
// 2) fused dequant GEMM: C[m,n] = (sum_k A[m,k] * bf16(W[n,k]*WS[n,k/GS])) * rs[m]
//    Tile BM(M) x BN(N), BK=64, double-buffered, ONE barrier per K-tile.
//    blockIdx.x = M-TILE (fastest): consecutive blocks share the same W/WS
//    tile -> L2/L3 reuse instead of HBM re-fetch.
// ---------------------------------------------------------------------------
__device__ __forceinline__ void gload_lds16(const bf16* g, bf16* l) {
  __builtin_amdgcn_global_load_lds(
      (const __attribute__((address_space(1))) void*)g,
      (__attribute__((address_space(3))) void*)l, 16, 0, 0);
}

template <int BM, int BN>
__global__ __launch_bounds__(256) void gemm_fused(
    const bf16* __restrict__ A, const float* __restrict__ W,
    const float* __restrict__ WS, const float* __restrict__ rs,
    float* __restrict__ C, int N, int K, int Kh, size_t part_stride) {
  constexpr int MI = BM / 32;            // M-frags per wave (wave tile BM/2)
  constexpr int NW = BN / 32;            // N-frags per wave (wave tile BN/2)
  constexpr int APASS = BM / 32;         // A staging instrs per thread
  constexpr int NPASS = BN / 32;         // B granules per thread
  __shared__ bf16 As[2][BM * 64];
  __shared__ bf16 Bs[2][BN * 64];
  const int tid = threadIdx.x;
  const int w = tid >> 6, l = tid & 63;
  const int row0 = blockIdx.x * BM;      // M-tile fastest!
  const int col0 = blockIdx.y * BN;
  const int z = blockIdx.z;
  const int wm = (w >> 1) * (BM / 2), wn = (w & 1) * (BN / 2);
  const int lcol = l & 15, quad = l >> 4;
  const int sr = l >> 3, sg = l & 7;
  const bf16* Ag = A + (size_t)row0 * K + (size_t)z * Kh;
  const int ksc = K / GS;

  int brow[NPASS], bj[NPASS];
#pragma unroll
  for (int p = 0; p < NPASS; ++p) {
    int gI = p * 256 + tid;
    brow[p] = gI >> 3;
    bj[p] = gI & 7;
  }

  float4 bl[NPASS][2];
  float bsc[NPASS];
  f32x4 acc[MI][NW] = {};

#define STAGE_A(buf, k0)                                                       \
  {                                                                            \
    _Pragma("unroll") for (int i = 0; i < APASS; ++i) {                        \
      int rb = w * (BM / 4) + i * 8;                                           \
      int r = rb + sr;                                                         \
      gload_lds16(Ag + (size_t)r * K + (k0) + ((sg ^ (r & 7)) * 8),            \
                  &As[buf][rb * 64]);                                          \
    }                                                                          \
  }
#define LOAD_B(k0)                                                             \
  {                                                                            \
    int grp = (z * Kh + (k0)) / GS;                                            \
    _Pragma("unroll") for (int p = 0; p < NPASS; ++p) {                        \
      const float* wp =                                                        \
          W + (size_t)(col0 + brow[p]) * K + (size_t)z * Kh + (k0) + bj[p] * 8;\
      bl[p][0] = *(const float4*)wp;                                           \
      bl[p][1] = *(const float4*)(wp + 4);                                     \
      bsc[p] = WS[(size_t)(col0 + brow[p]) * ksc + grp];                       \
    }                                                                          \
  }
#define WRITE_B(buf)                                                           \
  {                                                                            \
    _Pragma("unroll") for (int p = 0; p < NPASS; ++p) {                        \
      float sc = bsc[p];                                                       \
      bf16x8 o;                                                                \
      o[0] = (bf16)(bl[p][0].x * sc); o[1] = (bf16)(bl[p][0].y * sc);          \
      o[2] = (bf16)(bl[p][0].z * sc); o[3] = (bf16)(bl[p][0].w * sc);          \
      o[4] = (bf16)(bl[p][1].x * sc); o[5] = (bf16)(bl[p][1].y * sc);          \
      o[6] = (bf16)(bl[p][1].z * sc); o[7] = (bf16)(bl[p][1].w * sc);          \
      *(bf16x8*)&Bs[buf][brow[p] * 64 + ((bj[p] ^ (brow[p] & 7)) * 8)] = o;    \
    }                                                                          \
  }

  STAGE_A(0, 0)
  LOAD_B(0)
  WRITE_B(0)
  __syncthreads();

  int buf = 0;
  for (int k0 = 0; k0 < Kh; k0 += 64) {
    const bool has_next = (k0 + 64) < Kh;
    if (has_next) {
      STAGE_A(buf ^ 1, k0 + 64)
      LOAD_B(k0 + 64)
    }
#pragma unroll
    for (int ks = 0; ks < 2; ++ks) {
      bf16x8 af[MI], bff[NW];
#pragma unroll
      for (int mi = 0; mi < MI; ++mi) {
        int R = wm + mi * 16 + lcol;
        af[mi] = *(const bf16x8*)(&As[buf][R * 64 + (((ks * 4 + quad) ^ (R & 7)) * 8)]);
      }
#pragma unroll
      for (int ni = 0; ni < NW; ++ni) {
        int R = wn + ni * 16 + lcol;
        bff[ni] = *(const bf16x8*)(&Bs[buf][R * 64 + (((ks * 4 + quad) ^ (R & 7)) * 8)]);
      }
#pragma unroll
      for (int mi = 0; mi < MI; ++mi)
#pragma unroll
        for (int ni = 0; ni < NW; ++ni)
          acc[mi][ni] = __builtin_amdgcn_mfma_f32_16x16x32_bf16(
              af[mi], bff[ni], acc[mi][ni], 0, 0, 0);
    }
    if (has_next) WRITE_B(buf ^ 1)
    __syncthreads();
    buf ^= 1;
  }
#undef STAGE_A
#undef LOAD_B
#undef WRITE_B

  float* Cp = C + (size_t)z * part_stride;
#pragma unroll
  for (int mi = 0; mi < MI; ++mi) {
#pragma unroll
    for (int ni = 0; ni < NW; ++ni) {
      int col = col0 + wn + ni * 16 + lcol;
#pragma unroll
      for (int r = 0; r < 4; ++r) {
        int row = row0 + wm + mi * 16 + quad * 4 + r;
        Cp[(size_t)row * N + col] = acc[mi][ni][r] * rs[row];
      }
    }
  }
}

// ---------------------------------------------------------------------------
// 4a) q/k postprocess: sum split-K partials + rmsnorm + rope; bf16 out.
// ---------------------------------------------------------------------------
__global__ void qk_post(const float* __restrict__ qkvA, const float* __restrict__ qkvB,
                        const float* __restrict__ qw, const float* __restrict__ kw,
                        bf16* __restrict__ Qo, bf16* __restrict__ Ko) {
  const int t = blockIdx.x, h = blockIdx.y, i = threadIdx.x;
  const size_t off = (h < NH)
      ? (size_t)t * QKV_OUT + h * HD
      : (size_t)t * QKV_OUT + 2560 + (h - NH) * HD;
  const float* s1 = qkvA + off;
  const float* s2 = qkvB + off;
  float x0 = s1[2 * i] + s2[2 * i];
  float x1 = s1[2 * i + 1] + s2[2 * i + 1];
  float ss = x0 * x0 + x1 * x1;
  for (int off2 = 1; off2 < 64; off2 <<= 1) ss += __shfl_xor(ss, off2);
  float r = rsqrtf(ss * (1.f / 128.f) + 1e-5f);
  const float* wv = (h < NH) ? qw : kw;
  float y0 = x0 * r * wv[2 * i];
  float y1 = x1 * r * wv[2 * i + 1];
  float inv_freq = powf(500000.f, -(float)(2 * i) * (1.f / 128.f));
  float ang = (float)t * inv_freq;
  float sn, cs;
  sincosf(ang, &sn, &cs);
  float o0 = y0 * cs - y1 * sn;
  float o1 = y0 * sn + y1 * cs;
  if (h < NH) {
    bf16* dst = Qo + ((size_t)t * NH + h) * HD + 2 * i;
    dst[0] = (bf16)o0; dst[1] = (bf16)o1;
  } else {
    bf16* dst = Ko + ((size_t)(h - NH) * SEQ + t) * HD + 2 * i;
    dst[0] = (bf16)o0; dst[1] = (bf16)o1;
  }
}

// ---------------------------------------------------------------------------
// 4b) V transpose: sum partials, fp32 [t][3200+g*128+d] -> Vt bf16 [g][d][t]
// ---------------------------------------------------------------------------
__global__ __launch_bounds__(256) void v_post(const float* __restrict__ qkvA,
                                              const float* __restrict__ qkvB,
                                              bf16* __restrict__ Vt) {
  const int t0 = blockIdx.x * 64, g = blockIdx.y;
  const int tid = threadIdx.x;
  __shared__ bf16 Ls[64 * 137];
  {
    const int tl = tid >> 4;
    const int d0 = (tid & 15) * 8;
#pragma unroll
    for (int pass = 0; pass < 4; ++pass) {
      int t = pass * 16 + tl;
      size_t off = (size_t)(t0 + t) * QKV_OUT + 3200 + g * HD + d0;
      float4 a = *(const float4*)(qkvA + off);
      float4 b = *(const float4*)(qkvA + off + 4);
      float4 a2 = *(const float4*)(qkvB + off);
      float4 b2 = *(const float4*)(qkvB + off + 4);
      bf16* dst = Ls + t * 137 + d0;
      dst[0] = (bf16)(a.x + a2.x); dst[1] = (bf16)(a.y + a2.y);
      dst[2] = (bf16)(a.z + a2.z); dst[3] = (bf16)(a.w + a2.w);
      dst[4] = (bf16)(b.x + b2.x); dst[5] = (bf16)(b.y + b2.y);
      dst[6] = (bf16)(b.z + b2.z); dst[7] = (bf16)(b.w + b2.w);
    }
  }
  __syncthreads();
  {
    const int dl = tid >> 3;
    const int tl0 = (tid & 7) * 8;
#pragma unroll
    for (int pass = 0; pass < 4; ++pass) {
      int d = pass * 32 + dl;
      bf16x8 v;
#pragma unroll
      for (int j = 0; j < 8; ++j) v[j] = Ls[(tl0 + j) * 137 + d];
      *(bf16x8*)(Vt + ((size_t)g * HD + d) * SEQ + t0 + tl0) = v;
    }
  }
}

// ---------------------------------------------------------------------------
// 5) MFMA GQA causal flash attention (round-9 structure, unchanged).
// ---------------------------------------------------------------------------
__global__ __launch_bounds__(256) void attn_mfma(
    const bf16* __restrict__ Qb, const bf16* __restrict__ Kb,
    const bf16* __restrict__ Vt, bf16* __restrict__ O) {
  const int qb = 31 - (int)blockIdx.x;     // long blocks first
  const int hp = blockIdx.y;
  const int tid = threadIdx.x;
  const int wave = tid >> 6, lane = tid & 63;
  const int H = (hp >> 1) * 4 + (hp & 1) * 2 + (wave >> 1);
  const int g = H >> 2;
  const int qcol = lane & 15, quad = lane >> 4;
  const int q_tok = qb * 32 + (wave & 1) * 16 + qcol;
  const float scale = 0.08838834764831843f;

  __shared__ bf16 Ks[2][64 * 128];
  __shared__ bf16 Vs[2][128 * 64];

  const bf16* kbase = Kb + (size_t)g * SEQ * HD;
  const bf16* vbase = Vt + (size_t)g * HD * SEQ;

  bf16x8 qf[4];
  {
    const bf16* qp = Qb + ((size_t)q_tok * NH + H) * HD + quad * 8;
#pragma unroll
    for (int kc = 0; kc < 4; ++kc) qf[kc] = *(const bf16x8*)(qp + kc * 32);
  }

  float m_i = -1e30f, l_i = 0.f;
  f32x4 o_acc[8] = {};
  const int kt_max = (qb * 32 + 31) >> 6;

  const int k_r = lane >> 4, k_g = lane & 15;
  const int v_r = lane >> 3, v_g = lane & 7;

#define STAGE(buf, key0)                                                       \
  {                                                                            \
    _Pragma("unroll") for (int p = 0; p < 4; ++p) {                            \
      int r0 = wave * 16 + p * 4;                                              \
      int r = r0 + k_r;                                                        \
      gload_lds16(kbase + (size_t)((key0) + r) * HD + ((k_g ^ (r & 15)) * 8),  \
                  &Ks[buf][r0 * 128]);                                         \
    }                                                                          \
    _Pragma("unroll") for (int p = 0; p < 4; ++p) {                            \
      int r0 = wave * 32 + p * 8;                                              \
      int r = r0 + v_r;                                                        \
      gload_lds16(vbase + (size_t)r * SEQ + (key0) + ((v_g ^ (r & 7)) * 8),    \
                  &Vs[buf][r0 * 64]);                                          \
    }                                                                          \
  }

  STAGE(0, 0)

  for (int kt = 0; kt <= kt_max; ++kt) {
    const int key0 = kt * 64;
    __syncthreads();
    if (kt < kt_max) STAGE((kt + 1) & 1, key0 + 64)
    const bf16* Kt = Ks[kt & 1];
    const bf16* Vtile = Vs[kt & 1];

    f32x4 s[4];
#pragma unroll
    for (int mg = 0; mg < 4; ++mg) {
      const int R = mg * 16 + qcol;
      const bf16* krow = Kt + R * 128;
      f32x4 acc = {0.f, 0.f, 0.f, 0.f};
#pragma unroll
      for (int kc = 0; kc < 4; ++kc) {
        int j = kc * 4 + quad;
        bf16x8 kf = *(const bf16x8*)(krow + ((j ^ (R & 15)) * 8));
        acc = __builtin_amdgcn_mfma_f32_16x16x32_bf16(kf, qf[kc], acc, 0, 0, 0);
      }
      s[mg] = acc;
    }

    float mt = -1e30f;
#pragma unroll
    for (int mg = 0; mg < 4; ++mg)
#pragma unroll
      for (int r = 0; r < 4; ++r) {
        int key = key0 + mg * 16 + quad * 4 + r;
        float v = (key <= q_tok) ? s[mg][r] * scale : -1e30f;
        s[mg][r] = v;
        mt = fmaxf(mt, v);
      }
    mt = fmaxf(mt, __shfl_xor(mt, 16));
    mt = fmaxf(mt, __shfl_xor(mt, 32));
    float mnew = fmaxf(m_i, mt);
    float alpha = __expf(m_i - mnew);
    float ps = 0.f;
#pragma unroll
    for (int mg = 0; mg < 4; ++mg)
#pragma unroll
      for (int r = 0; r < 4; ++r) {
        float pv = __expf(s[mg][r] - mnew);
        s[mg][r] = pv;
        ps += pv;
      }
    ps += __shfl_xor(ps, 16);
    ps += __shfl_xor(ps, 32);
    l_i = l_i * alpha + ps;
    m_i = mnew;
#pragma unroll
    for (int mg2 = 0; mg2 < 8; ++mg2)
#pragma unroll
      for (int r = 0; r < 4; ++r) o_acc[mg2][r] *= alpha;

    bf16x8 pb[2];
#pragma unroll
    for (int c = 0; c < 2; ++c)
#pragma unroll
      for (int j = 0; j < 8; ++j)
        pb[c][j] = (bf16)s[c * 2 + (j >> 2)][j & 3];

#pragma unroll
    for (int mg2 = 0; mg2 < 8; ++mg2) {
      const int R = mg2 * 16 + qcol;
      const bf16* vrow = Vtile + R * 64;
      f32x4 acc = o_acc[mg2];
#pragma unroll
      for (int c = 0; c < 2; ++c) {
        int g8a = c * 8 + quad;
        int g8b = c * 8 + 4 + quad;
        bf16x4 v0 = *(const bf16x4*)(vrow + ((g8a >> 1) ^ (R & 7)) * 8 + (g8a & 1) * 4);
        bf16x4 v1 = *(const bf16x4*)(vrow + ((g8b >> 1) ^ (R & 7)) * 8 + (g8b & 1) * 4);
        bf16x8 vfr;
#pragma unroll
        for (int j = 0; j < 4; ++j) { vfr[j] = v0[j]; vfr[j + 4] = v1[j]; }
        acc = __builtin_amdgcn_mfma_f32_16x16x32_bf16(vfr, pb[c], acc, 0, 0, 0);
      }
      o_acc[mg2] = acc;
    }
  }
#undef STAGE

  const float inv = 1.f / l_i;
  bf16* op = O + (size_t)q_tok * DIM + H * HD + quad * 4;
#pragma unroll
  for (int mg2 = 0; mg2 < 8; ++mg2) {
    bf16x4 vv;
    vv[0] = (bf16)(o_acc[mg2][0] * inv);
    vv[1] = (bf16)(o_acc[mg2][1] * inv);
    vv[2] = (bf16)(o_acc[mg2][2] * inv);
    vv[3] = (bf16)(o_acc[mg2][3] * inv);
    *(bf16x4*)(op + mg2 * 16) = vv;
  }
}

// ---------------------------------------------------------------------------
extern "C" void kernel_launch(void* const* d_in, const int* in_sizes, int n_in,
                              void* d_out, int out_size, void* d_ws, size_t ws_size,
                              hipStream_t stream) {
  const float* x      = (const float*)d_in[0];
  const float* w_qkv  = (const float*)d_in[1];
  const float* ws_qkv = (const float*)d_in[2];
  const float* w_o    = (const float*)d_in[3];
  const float* ws_o   = (const float*)d_in[4];
  const float* qnw    = (const float*)d_in[5];
  const float* knw    = (const float*)d_in[6];
  float* out = (float*)d_out;

  char* p = (char*)d_ws;
  bf16*  act1 = (bf16*)p;  p += (size_t)SEQ * DIM * 2;
  float* rs1  = (float*)p; p += 4096;
  float* qkvA = (float*)p; p += (size_t)SEQ * QKV_OUT * 4;
  float* qkvB = (float*)p; p += (size_t)SEQ * QKV_OUT * 4;
  bf16*  Qb   = (bf16*)p;  p += (size_t)SEQ * NH * HD * 2;
  bf16*  Kb   = (bf16*)p;  p += (size_t)NKV * SEQ * HD * 2;
  bf16*  Vt   = (bf16*)p;  p += (size_t)NKV * HD * SEQ * 2;
  bf16*  attn = (bf16*)p;  p += (size_t)SEQ * DIM * 2;
  bf16*  act2 = (bf16*)p;  p += (size_t)SEQ * DIM * 2;
  float* rs2  = (float*)p; p += 4096;

  quant_kernel<float><<<SEQ, 256, 0, stream>>>(x, act1, rs1, DIM);
  // QKV GEMM: fused dequant, split-K x2, M-tile fastest for W reuse
  gemm_fused<128, 128><<<dim3(SEQ / 128, QKV_OUT / 128, 2), 256, 0, stream>>>(
      act1, w_qkv, ws_qkv, rs1, qkvA, QKV_OUT, DIM, DIM / 2, (size_t)SEQ * QKV_OUT);
  qk_post<<<dim3(SEQ, 25), 64, 0, stream>>>(qkvA, qkvB, qnw, knw, Qb, Kb);
  v_post<<<dim3(SEQ / 64, NKV), 256, 0, stream>>>(qkvA, qkvB, Vt);
  attn_mfma<<<dim3(32, 10), 256, 0, stream>>>(Qb, Kb, Vt, attn);
  quant_kernel<bf16><<<SEQ, 256, 0, stream>>>(attn, act2, rs2, DIM);
  // O-projection GEMM: fused dequant, full K, writes fp32 d_out directly
  gemm_fused<128, 64><<<dim3(SEQ / 128, DIM / 64, 1), 256, 0, stream>>>(
      act2, w_o, ws_o, rs2, out, DIM, DIM, DIM, 0);
}

// Round 12
// 239.178 us; speedup vs baseline: 1.2239x; 1.1634x over previous
//
#include <hip/hip_runtime.h>
#include <hip/hip_bf16.h>
#include <cstdint>
#include <math.h>

// Problem constants
#define SEQ 1024
#define DIM 2560
#define HD 128
#define NH 20
#define NKV 5
#define QKV_OUT 3840
#define GS 128

typedef __bf16 bf16;
typedef __bf16 bf16x4 __attribute__((ext_vector_type(4)));
typedef __bf16 bf16x8 __attribute__((ext_vector_type(8)));
typedef float f32x4 __attribute__((ext_vector_type(4)));

// ---------------------------------------------------------------------------
// 1) per-token activation quant (templated input dtype)
// ---------------------------------------------------------------------------
template <typename T>
__global__ __launch_bounds__(256) void quant_kernel(
    const T* __restrict__ x, bf16* __restrict__ act,
    float* __restrict__ rs, int cols) {
  const int row = blockIdx.x;
  const int tid = threadIdx.x;
  const T* xr = x + (size_t)row * cols;
  float m = 0.f;
  for (int i = tid; i < cols; i += 256) m = fmaxf(m, fabsf((float)xr[i]));
  for (int off = 32; off; off >>= 1) m = fmaxf(m, __shfl_xor(m, off));
  __shared__ float red[4];
  __shared__ float s_bc;
  if ((tid & 63) == 0) red[tid >> 6] = m;
  __syncthreads();
  if (tid == 0) {
    float mm = fmaxf(fmaxf(red[0], red[1]), fmaxf(red[2], red[3]));
    mm = fmaxf(mm, 1e-5f);
    s_bc = 127.f / mm;
    rs[row] = mm / 127.f;
  }
  __syncthreads();
  const float s = s_bc;
  bf16* ar = act + (size_t)row * cols;
  for (int i = tid; i < cols; i += 256) {
    float q = rintf((float)xr[i] * s);
    q = fminf(fmaxf(q, -128.f), 127.f);
    ar[i] = (bf16)q;
  }
}

// ---------------------------------------------------------------------------
// 2) merged weight dequant for both weight matrices (K = DIM for both)
// ---------------------------------------------------------------------------
__global__ __launch_bounds__(256) void dequant2_kernel(
    const float* __restrict__ w1, const float* __restrict__ ws1, bf16* __restrict__ o1,
    const float* __restrict__ w2, const float* __restrict__ ws2, bf16* __restrict__ o2,
    long n1_4, long total4) {
  long i = (long)blockIdx.x * 256 + threadIdx.x;
  if (i >= total4) return;
  const float* w; const float* ws; bf16* o; long e;
  if (i < n1_4) { w = w1; ws = ws1; o = o1; e = i * 4; }
  else          { w = w2; ws = ws2; o = o2; e = (i - n1_4) * 4; }
  int row = (int)(e / DIM);
  int k = (int)(e % DIM);
  float sc = ws[(size_t)row * (DIM / GS) + (k / GS)];
  float4 wv = *(const float4*)(w + e);
  bf16x4 ov;
  ov[0] = (bf16)(wv.x * sc);
  ov[1] = (bf16)(wv.y * sc);
  ov[2] = (bf16)(wv.z * sc);
  ov[3] = (bf16)(wv.w * sc);
  *(bf16x4*)(o + e) = ov;
}

// ---------------------------------------------------------------------------
// 3) bf16 MFMA GEMM, single-barrier double-buffered pipeline, XOR swizzle.
//    C[m,n] = (sum_k A[m,k]*B[n,k]) * rs[m]; A,B bf16 row-major [.,K].
//    1-D grid, decode: m = b / ND (XCD-friendly: W-tile sharers spaced ND);
//    nz = b % ND; n = nz % NN; z = nz / NN (split-K).
// ---------------------------------------------------------------------------
__device__ __forceinline__ void gload_lds16(const bf16* g, bf16* l) {
  __builtin_amdgcn_global_load_lds(
      (const __attribute__((address_space(1))) void*)g,
      (__attribute__((address_space(3))) void*)l, 16, 0, 0);
}

template <int BM, int BN>
__global__ __launch_bounds__(256) void gemm_pipe(
    const bf16* __restrict__ A, const bf16* __restrict__ B,
    const float* __restrict__ rs, float* __restrict__ C,
    int N, int K, int Kh, size_t part_stride, int ND, int NN) {
  constexpr int MI = BM / 32;
  constexpr int NW = BN / 32;
  constexpr int APASS = BM / 32;
  constexpr int BPASS = BN / 32;
  __shared__ bf16 As[2][BM * 64];
  __shared__ bf16 Bs[2][BN * 64];
  const int b = (int)blockIdx.x;
  const int mtile = b / ND;
  const int nz = b % ND;
  const int ntile = nz % NN;
  const int z = nz / NN;
  const int tid = threadIdx.x;
  const int w = tid >> 6, l = tid & 63;
  const int row0 = mtile * BM;
  const int col0 = ntile * BN;
  const int wm = (w >> 1) * (BM / 2), wn = (w & 1) * (BN / 2);
  const int lcol = l & 15, quad = l >> 4;
  const int sr = l >> 3, sg = l & 7;
  const bf16* Ag = A + (size_t)row0 * K + (size_t)z * Kh;
  const bf16* Bg = B + (size_t)col0 * K + (size_t)z * Kh;

  f32x4 acc[MI][NW] = {};

#define STAGE_AB(buf, k0)                                                      \
  {                                                                            \
    _Pragma("unroll") for (int i = 0; i < APASS; ++i) {                        \
      int rb = w * (BM / 4) + i * 8;                                           \
      int r = rb + sr;                                                         \
      gload_lds16(Ag + (size_t)r * K + (k0) + ((sg ^ (r & 7)) * 8),            \
                  &As[buf][rb * 64]);                                          \
    }                                                                          \
    _Pragma("unroll") for (int i = 0; i < BPASS; ++i) {                        \
      int rb = w * (BN / 4) + i * 8;                                           \
      int r = rb + sr;                                                         \
      gload_lds16(Bg + (size_t)r * K + (k0) + ((sg ^ (r & 7)) * 8),            \
                  &Bs[buf][rb * 64]);                                          \
    }                                                                          \
  }

  STAGE_AB(0, 0)
  __syncthreads();   // tile 0 staged

  int buf = 0;
  for (int k0 = 0; k0 < Kh; k0 += 64) {
    if (k0 + 64 < Kh) STAGE_AB(buf ^ 1, k0 + 64)
#pragma unroll
    for (int ks = 0; ks < 2; ++ks) {
      bf16x8 af[MI], bff[NW];
#pragma unroll
      for (int mi = 0; mi < MI; ++mi) {
        int R = wm + mi * 16 + lcol;
        af[mi] = *(const bf16x8*)(&As[buf][R * 64 + (((ks * 4 + quad) ^ (R & 7)) * 8)]);
      }
#pragma unroll
      for (int ni = 0; ni < NW; ++ni) {
        int R = wn + ni * 16 + lcol;
        bff[ni] = *(const bf16x8*)(&Bs[buf][R * 64 + (((ks * 4 + quad) ^ (R & 7)) * 8)]);
      }
#pragma unroll
      for (int mi = 0; mi < MI; ++mi)
#pragma unroll
        for (int ni = 0; ni < NW; ++ni)
          acc[mi][ni] = __builtin_amdgcn_mfma_f32_16x16x32_bf16(
              af[mi], bff[ni], acc[mi][ni], 0, 0, 0);
    }
    __syncthreads();   // drains next-tile glds (vmcnt) + all reads of buf
    buf ^= 1;
  }
#undef STAGE_AB

  float* Cp = C + (size_t)z * part_stride;
#pragma unroll
  for (int mi = 0; mi < MI; ++mi) {
#pragma unroll
    for (int ni = 0; ni < NW; ++ni) {
      int col = col0 + wn + ni * 16 + lcol;
#pragma unroll
      for (int r = 0; r < 4; ++r) {
        int row = row0 + wm + mi * 16 + quad * 4 + r;
        Cp[(size_t)row * N + col] = acc[mi][ni][r] * rs[row];
      }
    }
  }
}

// ---------------------------------------------------------------------------
// 4a) q/k postprocess: sum split-K partials + rmsnorm + rope; bf16 out.
// ---------------------------------------------------------------------------
__global__ void qk_post(const float* __restrict__ qkvA, const float* __restrict__ qkvB,
                        const float* __restrict__ qw, const float* __restrict__ kw,
                        bf16* __restrict__ Qo, bf16* __restrict__ Ko) {
  const int t = blockIdx.x, h = blockIdx.y, i = threadIdx.x;
  const size_t off = (h < NH)
      ? (size_t)t * QKV_OUT + h * HD
      : (size_t)t * QKV_OUT + 2560 + (h - NH) * HD;
  const float* s1 = qkvA + off;
  const float* s2 = qkvB + off;
  float x0 = s1[2 * i] + s2[2 * i];
  float x1 = s1[2 * i + 1] + s2[2 * i + 1];
  float ss = x0 * x0 + x1 * x1;
  for (int off2 = 1; off2 < 64; off2 <<= 1) ss += __shfl_xor(ss, off2);
  float r = rsqrtf(ss * (1.f / 128.f) + 1e-5f);
  const float* wv = (h < NH) ? qw : kw;
  float y0 = x0 * r * wv[2 * i];
  float y1 = x1 * r * wv[2 * i + 1];
  float inv_freq = powf(500000.f, -(float)(2 * i) * (1.f / 128.f));
  float ang = (float)t * inv_freq;
  float sn, cs;
  sincosf(ang, &sn, &cs);
  float o0 = y0 * cs - y1 * sn;
  float o1 = y0 * sn + y1 * cs;
  if (h < NH) {
    bf16* dst = Qo + ((size_t)t * NH + h) * HD + 2 * i;
    dst[0] = (bf16)o0; dst[1] = (bf16)o1;
  } else {
    bf16* dst = Ko + ((size_t)(h - NH) * SEQ + t) * HD + 2 * i;
    dst[0] = (bf16)o0; dst[1] = (bf16)o1;
  }
}

// ---------------------------------------------------------------------------
// 4b) V transpose: sum partials, fp32 [t][3200+g*128+d] -> Vt bf16 [g][d][t]
// ---------------------------------------------------------------------------
__global__ __launch_bounds__(256) void v_post(const float* __restrict__ qkvA,
                                              const float* __restrict__ qkvB,
                                              bf16* __restrict__ Vt) {
  const int t0 = blockIdx.x * 64, g = blockIdx.y;
  const int tid = threadIdx.x;
  __shared__ bf16 Ls[64 * 137];
  {
    const int tl = tid >> 4;
    const int d0 = (tid & 15) * 8;
#pragma unroll
    for (int pass = 0; pass < 4; ++pass) {
      int t = pass * 16 + tl;
      size_t off = (size_t)(t0 + t) * QKV_OUT + 3200 + g * HD + d0;
      float4 a = *(const float4*)(qkvA + off);
      float4 b = *(const float4*)(qkvA + off + 4);
      float4 a2 = *(const float4*)(qkvB + off);
      float4 b2 = *(const float4*)(qkvB + off + 4);
      bf16* dst = Ls + t * 137 + d0;
      dst[0] = (bf16)(a.x + a2.x); dst[1] = (bf16)(a.y + a2.y);
      dst[2] = (bf16)(a.z + a2.z); dst[3] = (bf16)(a.w + a2.w);
      dst[4] = (bf16)(b.x + b2.x); dst[5] = (bf16)(b.y + b2.y);
      dst[6] = (bf16)(b.z + b2.z); dst[7] = (bf16)(b.w + b2.w);
    }
  }
  __syncthreads();
  {
    const int dl = tid >> 3;
    const int tl0 = (tid & 7) * 8;
#pragma unroll
    for (int pass = 0; pass < 4; ++pass) {
      int d = pass * 32 + dl;
      bf16x8 v;
#pragma unroll
      for (int j = 0; j < 8; ++j) v[j] = Ls[(tl0 + j) * 137 + d];
      *(bf16x8*)(Vt + ((size_t)g * HD + d) * SEQ + t0 + tl0) = v;
    }
  }
}

// ---------------------------------------------------------------------------
// 5) MFMA GQA causal flash attention (unchanged).
// ---------------------------------------------------------------------------
__global__ __launch_bounds__(256) void attn_mfma(
    const bf16* __restrict__ Qb, const bf16* __restrict__ Kb,
    const bf16* __restrict__ Vt, bf16* __restrict__ O) {
  const int qb = 31 - (int)blockIdx.x;     // long blocks first
  const int hp = blockIdx.y;
  const int tid = threadIdx.x;
  const int wave = tid >> 6, lane = tid & 63;
  const int H = (hp >> 1) * 4 + (hp & 1) * 2 + (wave >> 1);
  const int g = H >> 2;
  const int qcol = lane & 15, quad = lane >> 4;
  const int q_tok = qb * 32 + (wave & 1) * 16 + qcol;
  const float scale = 0.08838834764831843f;

  __shared__ bf16 Ks[2][64 * 128];
  __shared__ bf16 Vs[2][128 * 64];

  const bf16* kbase = Kb + (size_t)g * SEQ * HD;
  const bf16* vbase = Vt + (size_t)g * HD * SEQ;

  bf16x8 qf[4];
  {
    const bf16* qp = Qb + ((size_t)q_tok * NH + H) * HD + quad * 8;
#pragma unroll
    for (int kc = 0; kc < 4; ++kc) qf[kc] = *(const bf16x8*)(qp + kc * 32);
  }

  float m_i = -1e30f, l_i = 0.f;
  f32x4 o_acc[8] = {};
  const int kt_max = (qb * 32 + 31) >> 6;

  const int k_r = lane >> 4, k_g = lane & 15;
  const int v_r = lane >> 3, v_g = lane & 7;

#define STAGE(buf, key0)                                                       \
  {                                                                            \
    _Pragma("unroll") for (int p = 0; p < 4; ++p) {                            \
      int r0 = wave * 16 + p * 4;                                              \
      int r = r0 + k_r;                                                        \
      gload_lds16(kbase + (size_t)((key0) + r) * HD + ((k_g ^ (r & 15)) * 8),  \
                  &Ks[buf][r0 * 128]);                                         \
    }                                                                          \
    _Pragma("unroll") for (int p = 0; p < 4; ++p) {                            \
      int r0 = wave * 32 + p * 8;                                              \
      int r = r0 + v_r;                                                        \
      gload_lds16(vbase + (size_t)r * SEQ + (key0) + ((v_g ^ (r & 7)) * 8),    \
                  &Vs[buf][r0 * 64]);                                          \
    }                                                                          \
  }

  STAGE(0, 0)

  for (int kt = 0; kt <= kt_max; ++kt) {
    const int key0 = kt * 64;
    __syncthreads();
    if (kt < kt_max) STAGE((kt + 1) & 1, key0 + 64)
    const bf16* Kt = Ks[kt & 1];
    const bf16* Vtile = Vs[kt & 1];

    f32x4 s[4];
#pragma unroll
    for (int mg = 0; mg < 4; ++mg) {
      const int R = mg * 16 + qcol;
      const bf16* krow = Kt + R * 128;
      f32x4 acc = {0.f, 0.f, 0.f, 0.f};
#pragma unroll
      for (int kc = 0; kc < 4; ++kc) {
        int j = kc * 4 + quad;
        bf16x8 kf = *(const bf16x8*)(krow + ((j ^ (R & 15)) * 8));
        acc = __builtin_amdgcn_mfma_f32_16x16x32_bf16(kf, qf[kc], acc, 0, 0, 0);
      }
      s[mg] = acc;
    }

    float mt = -1e30f;
#pragma unroll
    for (int mg = 0; mg < 4; ++mg)
#pragma unroll
      for (int r = 0; r < 4; ++r) {
        int key = key0 + mg * 16 + quad * 4 + r;
        float v = (key <= q_tok) ? s[mg][r] * scale : -1e30f;
        s[mg][r] = v;
        mt = fmaxf(mt, v);
      }
    mt = fmaxf(mt, __shfl_xor(mt, 16));
    mt = fmaxf(mt, __shfl_xor(mt, 32));
    float mnew = fmaxf(m_i, mt);
    float alpha = __expf(m_i - mnew);
    float ps = 0.f;
#pragma unroll
    for (int mg = 0; mg < 4; ++mg)
#pragma unroll
      for (int r = 0; r < 4; ++r) {
        float pv = __expf(s[mg][r] - mnew);
        s[mg][r] = pv;
        ps += pv;
      }
    ps += __shfl_xor(ps, 16);
    ps += __shfl_xor(ps, 32);
    l_i = l_i * alpha + ps;
    m_i = mnew;
#pragma unroll
    for (int mg2 = 0; mg2 < 8; ++mg2)
#pragma unroll
      for (int r = 0; r < 4; ++r) o_acc[mg2][r] *= alpha;

    bf16x8 pb[2];
#pragma unroll
    for (int c = 0; c < 2; ++c)
#pragma unroll
      for (int j = 0; j < 8; ++j)
        pb[c][j] = (bf16)s[c * 2 + (j >> 2)][j & 3];

#pragma unroll
    for (int mg2 = 0; mg2 < 8; ++mg2) {
      const int R = mg2 * 16 + qcol;
      const bf16* vrow = Vtile + R * 64;
      f32x4 acc = o_acc[mg2];
#pragma unroll
      for (int c = 0; c < 2; ++c) {
        int g8a = c * 8 + quad;
        int g8b = c * 8 + 4 + quad;
        bf16x4 v0 = *(const bf16x4*)(vrow + ((g8a >> 1) ^ (R & 7)) * 8 + (g8a & 1) * 4);
        bf16x4 v1 = *(const bf16x4*)(vrow + ((g8b >> 1) ^ (R & 7)) * 8 + (g8b & 1) * 4);
        bf16x8 vfr;
#pragma unroll
        for (int j = 0; j < 4; ++j) { vfr[j] = v0[j]; vfr[j + 4] = v1[j]; }
        acc = __builtin_amdgcn_mfma_f32_16x16x32_bf16(vfr, pb[c], acc, 0, 0, 0);
      }
      o_acc[mg2] = acc;
    }
  }
#undef STAGE

  const float inv = 1.f / l_i;
  bf16* op = O + (size_t)q_tok * DIM + H * HD + quad * 4;
#pragma unroll
  for (int mg2 = 0; mg2 < 8; ++mg2) {
    bf16x4 vv;
    vv[0] = (bf16)(o_acc[mg2][0] * inv);
    vv[1] = (bf16)(o_acc[mg2][1] * inv);
    vv[2] = (bf16)(o_acc[mg2][2] * inv);
    vv[3] = (bf16)(o_acc[mg2][3] * inv);
    *(bf16x4*)(op + mg2 * 16) = vv;
  }
}

// ---------------------------------------------------------------------------
extern "C" void kernel_launch(void* const* d_in, const int* in_sizes, int n_in,
                              void* d_out, int out_size, void* d_ws, size_t ws_size,
                              hipStream_t stream) {
  const float* x      = (const float*)d_in[0];
  const float* w_qkv  = (const float*)d_in[1];
  const float* ws_qkv = (const float*)d_in[2];
  const float* w_o    = (const float*)d_in[3];
  const float* ws_o   = (const float*)d_in[4];
  const float* qnw    = (const float*)d_in[5];
  const float* knw    = (const float*)d_in[6];
  float* out = (float*)d_out;

  char* p = (char*)d_ws;
  bf16*  act1 = (bf16*)p;  p += (size_t)SEQ * DIM * 2;
  float* rs1  = (float*)p; p += 4096;
  bf16*  wqdq = (bf16*)p;  p += (size_t)QKV_OUT * DIM * 2;
  bf16*  wodq = (bf16*)p;  p += (size_t)DIM * DIM * 2;
  float* qkvA = (float*)p; p += (size_t)SEQ * QKV_OUT * 4;
  float* qkvB = (float*)p; p += (size_t)SEQ * QKV_OUT * 4;
  bf16*  Qb   = (bf16*)p;  p += (size_t)SEQ * NH * HD * 2;
  bf16*  Kb   = (bf16*)p;  p += (size_t)NKV * SEQ * HD * 2;
  bf16*  Vt   = (bf16*)p;  p += (size_t)NKV * HD * SEQ * 2;
  bf16*  attn = (bf16*)p;  p += (size_t)SEQ * DIM * 2;
  bf16*  act2 = (bf16*)p;  p += (size_t)SEQ * DIM * 2;
  float* rs2  = (float*)p; p += 4096;

  quant_kernel<float><<<SEQ, 256, 0, stream>>>(x, act1, rs1, DIM);
  {
    long n1_4 = (long)QKV_OUT * DIM / 4;
    long total4 = n1_4 + (long)DIM * DIM / 4;
    dequant2_kernel<<<(int)((total4 + 255) / 256), 256, 0, stream>>>(
        w_qkv, ws_qkv, wqdq, w_o, ws_o, wodq, n1_4, total4);
  }
  // GEMM1: BM=128, BN=128, split-K x2. Grid 480 1-D: m = b/60 (W sharers
  // spaced 60 -> 2 XCDs), nz = b%60, n = nz%30, z = nz/30.
  gemm_pipe<128, 128><<<480, 256, 0, stream>>>(
      act1, wqdq, rs1, qkvA, QKV_OUT, DIM, DIM / 2, (size_t)SEQ * QKV_OUT, 60, 30);
  qk_post<<<dim3(SEQ, 25), 64, 0, stream>>>(qkvA, qkvB, qnw, knw, Qb, Kb);
  v_post<<<dim3(SEQ / 64, NKV), 256, 0, stream>>>(qkvA, qkvB, Vt);
  attn_mfma<<<dim3(32, 10), 256, 0, stream>>>(Qb, Kb, Vt, attn);
  quant_kernel<bf16><<<SEQ, 256, 0, stream>>>(attn, act2, rs2, DIM);
  // GEMM2: BM=64, BN=64, full K. Grid 640 1-D: m = b/40 (sharers spaced 40
  // = 0 mod 8 -> same XCD, W fetched once), n = b%40, z = 0.
  gemm_pipe<64, 64><<<640, 256, 0, stream>>>(
      act2, wodq, rs2, out, DIM, DIM, DIM, 0, 40, 40);
}

// Round 13
// 232.433 us; speedup vs baseline: 1.2594x; 1.0290x over previous
//
#include <hip/hip_runtime.h>
#include <hip/hip_bf16.h>
#include <cstdint>
#include <math.h>

// Problem constants
#define SEQ 1024
#define DIM 2560
#define HD 128
#define NH 20
#define NKV 5
#define QKV_OUT 3840
#define GS 128

typedef __bf16 bf16;
typedef __bf16 bf16x4 __attribute__((ext_vector_type(4)));
typedef __bf16 bf16x8 __attribute__((ext_vector_type(8)));
typedef float f32x4 __attribute__((ext_vector_type(4)));

// ---------------------------------------------------------------------------
// 1) per-token activation quant (standalone, used for attn output)
// ---------------------------------------------------------------------------
template <typename T>
__global__ __launch_bounds__(256) void quant_kernel(
    const T* __restrict__ x, bf16* __restrict__ act,
    float* __restrict__ rs, int cols) {
  const int row = blockIdx.x;
  const int tid = threadIdx.x;
  const T* xr = x + (size_t)row * cols;
  float m = 0.f;
  for (int i = tid; i < cols; i += 256) m = fmaxf(m, fabsf((float)xr[i]));
  for (int off = 32; off; off >>= 1) m = fmaxf(m, __shfl_xor(m, off));
  __shared__ float red[4];
  __shared__ float s_bc;
  if ((tid & 63) == 0) red[tid >> 6] = m;
  __syncthreads();
  if (tid == 0) {
    float mm = fmaxf(fmaxf(red[0], red[1]), fmaxf(red[2], red[3]));
    mm = fmaxf(mm, 1e-5f);
    s_bc = 127.f / mm;
    rs[row] = mm / 127.f;
  }
  __syncthreads();
  const float s = s_bc;
  bf16* ar = act + (size_t)row * cols;
  for (int i = tid; i < cols; i += 256) {
    float q = rintf((float)xr[i] * s);
    q = fminf(fmaxf(q, -128.f), 127.f);
    ar[i] = (bf16)q;
  }
}

// ---------------------------------------------------------------------------
// 1b) fused pre-pass: blocks [0,SEQ) = activation quant of x;
//     blocks [SEQ, ...) = merged weight dequant (both matrices, K=DIM)
// ---------------------------------------------------------------------------
__global__ __launch_bounds__(256) void fused_pre(
    const float* __restrict__ x, bf16* __restrict__ act, float* __restrict__ rs,
    const float* __restrict__ w1, const float* __restrict__ ws1, bf16* __restrict__ o1,
    const float* __restrict__ w2, const float* __restrict__ ws2, bf16* __restrict__ o2,
    long n1_4, long total4) {
  const int tid = threadIdx.x;
  if (blockIdx.x < SEQ) {
    const int row = blockIdx.x;
    const float* xr = x + (size_t)row * DIM;
    float m = 0.f;
    for (int i = tid; i < DIM; i += 256) m = fmaxf(m, fabsf(xr[i]));
    for (int off = 32; off; off >>= 1) m = fmaxf(m, __shfl_xor(m, off));
    __shared__ float red[4];
    __shared__ float s_bc;
    if ((tid & 63) == 0) red[tid >> 6] = m;
    __syncthreads();
    if (tid == 0) {
      float mm = fmaxf(fmaxf(red[0], red[1]), fmaxf(red[2], red[3]));
      mm = fmaxf(mm, 1e-5f);
      s_bc = 127.f / mm;
      rs[row] = mm / 127.f;
    }
    __syncthreads();
    const float s = s_bc;
    bf16* ar = act + (size_t)row * DIM;
    for (int i = tid; i < DIM; i += 256) {
      float q = rintf(xr[i] * s);
      q = fminf(fmaxf(q, -128.f), 127.f);
      ar[i] = (bf16)q;
    }
  } else {
    long i = (long)(blockIdx.x - SEQ) * 256 + tid;
    if (i >= total4) return;
    const float* w; const float* ws; bf16* o; long e;
    if (i < n1_4) { w = w1; ws = ws1; o = o1; e = i * 4; }
    else          { w = w2; ws = ws2; o = o2; e = (i - n1_4) * 4; }
    int row = (int)(e / DIM);
    int k = (int)(e % DIM);
    float sc = ws[(size_t)row * (DIM / GS) + (k / GS)];
    float4 wv = *(const float4*)(w + e);
    bf16x4 ov;
    ov[0] = (bf16)(wv.x * sc);
    ov[1] = (bf16)(wv.y * sc);
    ov[2] = (bf16)(wv.z * sc);
    ov[3] = (bf16)(wv.w * sc);
    *(bf16x4*)(o + e) = ov;
  }
}

// ---------------------------------------------------------------------------
// 3) bf16 MFMA GEMM, single-barrier double-buffered pipeline, XOR swizzle.
//    1-D grid decode: m = b/ND (W sharers spaced ND); nz = b%ND; n = nz%NN;
//    z = nz/NN (split-K).
// ---------------------------------------------------------------------------
__device__ __forceinline__ void gload_lds16(const bf16* g, bf16* l) {
  __builtin_amdgcn_global_load_lds(
      (const __attribute__((address_space(1))) void*)g,
      (__attribute__((address_space(3))) void*)l, 16, 0, 0);
}

template <int BM, int BN>
__global__ __launch_bounds__(256) void gemm_pipe(
    const bf16* __restrict__ A, const bf16* __restrict__ B,
    const float* __restrict__ rs, float* __restrict__ C,
    int N, int K, int Kh, size_t part_stride, int ND, int NN) {
  constexpr int MI = BM / 32;
  constexpr int NW = BN / 32;
  constexpr int APASS = BM / 32;
  constexpr int BPASS = BN / 32;
  __shared__ bf16 As[2][BM * 64];
  __shared__ bf16 Bs[2][BN * 64];
  const int b = (int)blockIdx.x;
  const int mtile = b / ND;
  const int nz = b % ND;
  const int ntile = nz % NN;
  const int z = nz / NN;
  const int tid = threadIdx.x;
  const int w = tid >> 6, l = tid & 63;
  const int row0 = mtile * BM;
  const int col0 = ntile * BN;
  const int wm = (w >> 1) * (BM / 2), wn = (w & 1) * (BN / 2);
  const int lcol = l & 15, quad = l >> 4;
  const int sr = l >> 3, sg = l & 7;
  const bf16* Ag = A + (size_t)row0 * K + (size_t)z * Kh;
  const bf16* Bg = B + (size_t)col0 * K + (size_t)z * Kh;

  f32x4 acc[MI][NW] = {};

#define STAGE_AB(buf, k0)                                                      \
  {                                                                            \
    _Pragma("unroll") for (int i = 0; i < APASS; ++i) {                        \
      int rb = w * (BM / 4) + i * 8;                                           \
      int r = rb + sr;                                                         \
      gload_lds16(Ag + (size_t)r * K + (k0) + ((sg ^ (r & 7)) * 8),            \
                  &As[buf][rb * 64]);                                          \
    }                                                                          \
    _Pragma("unroll") for (int i = 0; i < BPASS; ++i) {                        \
      int rb = w * (BN / 4) + i * 8;                                           \
      int r = rb + sr;                                                         \
      gload_lds16(Bg + (size_t)r * K + (k0) + ((sg ^ (r & 7)) * 8),            \
                  &Bs[buf][rb * 64]);                                          \
    }                                                                          \
  }

  STAGE_AB(0, 0)
  __syncthreads();

  int buf = 0;
  for (int k0 = 0; k0 < Kh; k0 += 64) {
    if (k0 + 64 < Kh) STAGE_AB(buf ^ 1, k0 + 64)
#pragma unroll
    for (int ks = 0; ks < 2; ++ks) {
      bf16x8 af[MI], bff[NW];
#pragma unroll
      for (int mi = 0; mi < MI; ++mi) {
        int R = wm + mi * 16 + lcol;
        af[mi] = *(const bf16x8*)(&As[buf][R * 64 + (((ks * 4 + quad) ^ (R & 7)) * 8)]);
      }
#pragma unroll
      for (int ni = 0; ni < NW; ++ni) {
        int R = wn + ni * 16 + lcol;
        bff[ni] = *(const bf16x8*)(&Bs[buf][R * 64 + (((ks * 4 + quad) ^ (R & 7)) * 8)]);
      }
#pragma unroll
      for (int mi = 0; mi < MI; ++mi)
#pragma unroll
        for (int ni = 0; ni < NW; ++ni)
          acc[mi][ni] = __builtin_amdgcn_mfma_f32_16x16x32_bf16(
              af[mi], bff[ni], acc[mi][ni], 0, 0, 0);
    }
    __syncthreads();
    buf ^= 1;
  }
#undef STAGE_AB

  float* Cp = C + (size_t)z * part_stride;
#pragma unroll
  for (int mi = 0; mi < MI; ++mi) {
#pragma unroll
    for (int ni = 0; ni < NW; ++ni) {
      int col = col0 + wn + ni * 16 + lcol;
#pragma unroll
      for (int r = 0; r < 4; ++r) {
        int row = row0 + wm + mi * 16 + quad * 4 + r;
        Cp[(size_t)row * N + col] = acc[mi][ni][r] * rs[row];
      }
    }
  }
}

// ---------------------------------------------------------------------------
// 4) fused post-pass: blocks [0,6400) = qk rmsnorm+rope (4 wave-units each);
//    blocks [6400, 6480) = V transpose (sum partials -> Vt bf16 [g][d][t]).
// ---------------------------------------------------------------------------
__global__ __launch_bounds__(256) void fused_post(
    const float* __restrict__ qkvA, const float* __restrict__ qkvB,
    const float* __restrict__ qw, const float* __restrict__ kw,
    bf16* __restrict__ Qo, bf16* __restrict__ Ko, bf16* __restrict__ Vt) {
  __shared__ bf16 Ls[64 * 137];
  const int bx = (int)blockIdx.x;
  const int tid = threadIdx.x;
  if (bx < 6400) {
    const int wave = tid >> 6, i = tid & 63;
    const int u = bx * 4 + wave;           // 0..25599
    const int t = u & 1023, h = u >> 10;   // h in 0..24
    const size_t off = (h < NH)
        ? (size_t)t * QKV_OUT + h * HD
        : (size_t)t * QKV_OUT + 2560 + (h - NH) * HD;
    const float* s1 = qkvA + off;
    const float* s2 = qkvB + off;
    float x0 = s1[2 * i] + s2[2 * i];
    float x1 = s1[2 * i + 1] + s2[2 * i + 1];
    float ss = x0 * x0 + x1 * x1;
    for (int off2 = 1; off2 < 64; off2 <<= 1) ss += __shfl_xor(ss, off2);
    float r = rsqrtf(ss * (1.f / 128.f) + 1e-5f);
    const float* wv = (h < NH) ? qw : kw;
    float y0 = x0 * r * wv[2 * i];
    float y1 = x1 * r * wv[2 * i + 1];
    float inv_freq = powf(500000.f, -(float)(2 * i) * (1.f / 128.f));
    float ang = (float)t * inv_freq;
    float sn, cs;
    sincosf(ang, &sn, &cs);
    float o0 = y0 * cs - y1 * sn;
    float o1 = y0 * sn + y1 * cs;
    if (h < NH) {
      bf16* dst = Qo + ((size_t)t * NH + h) * HD + 2 * i;
      dst[0] = (bf16)o0; dst[1] = (bf16)o1;
    } else {
      bf16* dst = Ko + ((size_t)(h - NH) * SEQ + t) * HD + 2 * i;
      dst[0] = (bf16)o0; dst[1] = (bf16)o1;
    }
  } else {
    const int b2 = bx - 6400;
    const int t0 = (b2 & 15) * 64, g = b2 >> 4;
    {
      const int tl = tid >> 4;
      const int d0 = (tid & 15) * 8;
#pragma unroll
      for (int pass = 0; pass < 4; ++pass) {
        int t = pass * 16 + tl;
        size_t off = (size_t)(t0 + t) * QKV_OUT + 3200 + g * HD + d0;
        float4 a = *(const float4*)(qkvA + off);
        float4 b = *(const float4*)(qkvA + off + 4);
        float4 a2 = *(const float4*)(qkvB + off);
        float4 b2v = *(const float4*)(qkvB + off + 4);
        bf16* dst = Ls + t * 137 + d0;
        dst[0] = (bf16)(a.x + a2.x); dst[1] = (bf16)(a.y + a2.y);
        dst[2] = (bf16)(a.z + a2.z); dst[3] = (bf16)(a.w + a2.w);
        dst[4] = (bf16)(b.x + b2v.x); dst[5] = (bf16)(b.y + b2v.y);
        dst[6] = (bf16)(b.z + b2v.z); dst[7] = (bf16)(b.w + b2v.w);
      }
    }
    __syncthreads();
    {
      const int dl = tid >> 3;
      const int tl0 = (tid & 7) * 8;
#pragma unroll
      for (int pass = 0; pass < 4; ++pass) {
        int d = pass * 32 + dl;
        bf16x8 v;
#pragma unroll
        for (int j = 0; j < 8; ++j) v[j] = Ls[(tl0 + j) * 137 + d];
        *(bf16x8*)(Vt + ((size_t)g * HD + d) * SEQ + t0 + tl0) = v;
      }
    }
  }
}

// ---------------------------------------------------------------------------
// 5) MFMA GQA causal flash attention. Round-9 structure + register-batched
//    fragment loads: all 16 K-frags and all 16 V-frag-pairs hoisted into
//    arrays before their consumers (pipelined lgkm waits instead of 48
//    serial ~120cyc ds_read->MFMA chains). launch_bounds(256,1): LDS already
//    caps CU at 8 waves, so the high-VGPR tier costs nothing.
// ---------------------------------------------------------------------------
__global__ __launch_bounds__(256, 1) void attn_mfma(
    const bf16* __restrict__ Qb, const bf16* __restrict__ Kb,
    const bf16* __restrict__ Vt, bf16* __restrict__ O) {
  const int qb = 31 - (int)blockIdx.x;     // long blocks first
  const int hp = blockIdx.y;
  const int tid = threadIdx.x;
  const int wave = tid >> 6, lane = tid & 63;
  const int H = (hp >> 1) * 4 + (hp & 1) * 2 + (wave >> 1);
  const int g = H >> 2;
  const int qcol = lane & 15, quad = lane >> 4;
  const int q_tok = qb * 32 + (wave & 1) * 16 + qcol;
  const float scale = 0.08838834764831843f;

  __shared__ bf16 Ks[2][64 * 128];
  __shared__ bf16 Vs[2][128 * 64];

  const bf16* kbase = Kb + (size_t)g * SEQ * HD;
  const bf16* vbase = Vt + (size_t)g * HD * SEQ;

  bf16x8 qf[4];
  {
    const bf16* qp = Qb + ((size_t)q_tok * NH + H) * HD + quad * 8;
#pragma unroll
    for (int kc = 0; kc < 4; ++kc) qf[kc] = *(const bf16x8*)(qp + kc * 32);
  }

  float m_i = -1e30f, l_i = 0.f;
  f32x4 o_acc[8] = {};
  const int kt_max = (qb * 32 + 31) >> 6;

  const int k_r = lane >> 4, k_g = lane & 15;
  const int v_r = lane >> 3, v_g = lane & 7;

#define STAGE(buf, key0)                                                       \
  {                                                                            \
    _Pragma("unroll") for (int p = 0; p < 4; ++p) {                            \
      int r0 = wave * 16 + p * 4;                                              \
      int r = r0 + k_r;                                                        \
      gload_lds16(kbase + (size_t)((key0) + r) * HD + ((k_g ^ (r & 15)) * 8),  \
                  &Ks[buf][r0 * 128]);                                         \
    }                                                                          \
    _Pragma("unroll") for (int p = 0; p < 4; ++p) {                            \
      int r0 = wave * 32 + p * 8;                                              \
      int r = r0 + v_r;                                                        \
      gload_lds16(vbase + (size_t)r * SEQ + (key0) + ((v_g ^ (r & 7)) * 8),    \
                  &Vs[buf][r0 * 64]);                                          \
    }                                                                          \
  }

  STAGE(0, 0)

  for (int kt = 0; kt <= kt_max; ++kt) {
    const int key0 = kt * 64;
    __syncthreads();
    if (kt < kt_max) STAGE((kt + 1) & 1, key0 + 64)
    const bf16* Kt = Ks[kt & 1];
    const bf16* Vtile = Vs[kt & 1];

    // ---- batched K fragment loads (16 ds_read_b128, no dependent use) ----
    bf16x8 kf[4][4];
#pragma unroll
    for (int mg = 0; mg < 4; ++mg) {
      const int R = mg * 16 + qcol;
      const bf16* krow = Kt + R * 128;
#pragma unroll
      for (int kc = 0; kc < 4; ++kc)
        kf[mg][kc] = *(const bf16x8*)(krow + (((kc * 4 + quad) ^ (R & 15)) * 8));
    }
    // ---- S^T = K · Q^T ----
    f32x4 s[4];
#pragma unroll
    for (int mg = 0; mg < 4; ++mg) {
      f32x4 acc = {0.f, 0.f, 0.f, 0.f};
#pragma unroll
      for (int kc = 0; kc < 4; ++kc)
        acc = __builtin_amdgcn_mfma_f32_16x16x32_bf16(kf[mg][kc], qf[kc], acc, 0, 0, 0);
      s[mg] = acc;
    }

    // ---- batched V fragment loads (32 ds_read_b64; overlap with softmax) --
    bf16x8 vf[8][2];
#pragma unroll
    for (int mg2 = 0; mg2 < 8; ++mg2) {
      const int R = mg2 * 16 + qcol;
      const bf16* vrow = Vtile + R * 64;
#pragma unroll
      for (int c = 0; c < 2; ++c) {
        int g8a = c * 8 + quad;
        int g8b = c * 8 + 4 + quad;
        bf16x4 v0 = *(const bf16x4*)(vrow + ((g8a >> 1) ^ (R & 7)) * 8 + (g8a & 1) * 4);
        bf16x4 v1 = *(const bf16x4*)(vrow + ((g8b >> 1) ^ (R & 7)) * 8 + (g8b & 1) * 4);
#pragma unroll
        for (int j = 0; j < 4; ++j) { vf[mg2][c][j] = v0[j]; vf[mg2][c][j + 4] = v1[j]; }
      }
    }

    // ---- scale + causal mask + online softmax ----
    float mt = -1e30f;
#pragma unroll
    for (int mg = 0; mg < 4; ++mg)
#pragma unroll
      for (int r = 0; r < 4; ++r) {
        int key = key0 + mg * 16 + quad * 4 + r;
        float v = (key <= q_tok) ? s[mg][r] * scale : -1e30f;
        s[mg][r] = v;
        mt = fmaxf(mt, v);
      }
    mt = fmaxf(mt, __shfl_xor(mt, 16));
    mt = fmaxf(mt, __shfl_xor(mt, 32));
    float mnew = fmaxf(m_i, mt);
    float alpha = __expf(m_i - mnew);
    float ps = 0.f;
#pragma unroll
    for (int mg = 0; mg < 4; ++mg)
#pragma unroll
      for (int r = 0; r < 4; ++r) {
        float pv = __expf(s[mg][r] - mnew);
        s[mg][r] = pv;
        ps += pv;
      }
    ps += __shfl_xor(ps, 16);
    ps += __shfl_xor(ps, 32);
    l_i = l_i * alpha + ps;
    m_i = mnew;
#pragma unroll
    for (int mg2 = 0; mg2 < 8; ++mg2)
#pragma unroll
      for (int r = 0; r < 4; ++r) o_acc[mg2][r] *= alpha;

    // ---- P^T B-frags from own regs (key = mg*16 + quad*4 + r) ----
    bf16x8 pb[2];
#pragma unroll
    for (int c = 0; c < 2; ++c)
#pragma unroll
      for (int j = 0; j < 8; ++j)
        pb[c][j] = (bf16)s[c * 2 + (j >> 2)][j & 3];

    // ---- O^T += V^T · P^T ----
#pragma unroll
    for (int mg2 = 0; mg2 < 8; ++mg2) {
      f32x4 acc = o_acc[mg2];
#pragma unroll
      for (int c = 0; c < 2; ++c)
        acc = __builtin_amdgcn_mfma_f32_16x16x32_bf16(vf[mg2][c], pb[c], acc, 0, 0, 0);
      o_acc[mg2] = acc;
    }
  }
#undef STAGE

  const float inv = 1.f / l_i;
  bf16* op = O + (size_t)q_tok * DIM + H * HD + quad * 4;
#pragma unroll
  for (int mg2 = 0; mg2 < 8; ++mg2) {
    bf16x4 vv;
    vv[0] = (bf16)(o_acc[mg2][0] * inv);
    vv[1] = (bf16)(o_acc[mg2][1] * inv);
    vv[2] = (bf16)(o_acc[mg2][2] * inv);
    vv[3] = (bf16)(o_acc[mg2][3] * inv);
    *(bf16x4*)(op + mg2 * 16) = vv;
  }
}

// ---------------------------------------------------------------------------
extern "C" void kernel_launch(void* const* d_in, const int* in_sizes, int n_in,
                              void* d_out, int out_size, void* d_ws, size_t ws_size,
                              hipStream_t stream) {
  const float* x      = (const float*)d_in[0];
  const float* w_qkv  = (const float*)d_in[1];
  const float* ws_qkv = (const float*)d_in[2];
  const float* w_o    = (const float*)d_in[3];
  const float* ws_o   = (const float*)d_in[4];
  const float* qnw    = (const float*)d_in[5];
  const float* knw    = (const float*)d_in[6];
  float* out = (float*)d_out;

  char* p = (char*)d_ws;
  bf16*  act1 = (bf16*)p;  p += (size_t)SEQ * DIM * 2;
  float* rs1  = (float*)p; p += 4096;
  bf16*  wqdq = (bf16*)p;  p += (size_t)QKV_OUT * DIM * 2;
  bf16*  wodq = (bf16*)p;  p += (size_t)DIM * DIM * 2;
  float* qkvA = (float*)p; p += (size_t)SEQ * QKV_OUT * 4;
  float* qkvB = (float*)p; p += (size_t)SEQ * QKV_OUT * 4;
  bf16*  Qb   = (bf16*)p;  p += (size_t)SEQ * NH * HD * 2;
  bf16*  Kb   = (bf16*)p;  p += (size_t)NKV * SEQ * HD * 2;
  bf16*  Vt   = (bf16*)p;  p += (size_t)NKV * HD * SEQ * 2;
  bf16*  attn = (bf16*)p;  p += (size_t)SEQ * DIM * 2;
  bf16*  act2 = (bf16*)p;  p += (size_t)SEQ * DIM * 2;
  float* rs2  = (float*)p; p += 4096;

  {
    long n1_4 = (long)QKV_OUT * DIM / 4;
    long total4 = n1_4 + (long)DIM * DIM / 4;
    int dq_blocks = (int)((total4 + 255) / 256);
    fused_pre<<<SEQ + dq_blocks, 256, 0, stream>>>(
        x, act1, rs1, w_qkv, ws_qkv, wqdq, w_o, ws_o, wodq, n1_4, total4);
  }
  // GEMM1: BM=128, BN=128, split-K x2. Grid 480 1-D: m = b/60, n = (b%60)%30,
  // z = (b%60)/30.
  gemm_pipe<128, 128><<<480, 256, 0, stream>>>(
      act1, wqdq, rs1, qkvA, QKV_OUT, DIM, DIM / 2, (size_t)SEQ * QKV_OUT, 60, 30);
  // fused qk rmsnorm+rope (6400 blocks) + V transpose (80 blocks)
  fused_post<<<6480, 256, 0, stream>>>(qkvA, qkvB, qnw, knw, Qb, Kb, Vt);
  attn_mfma<<<dim3(32, 10), 256, 0, stream>>>(Qb, Kb, Vt, attn);
  quant_kernel<bf16><<<SEQ, 256, 0, stream>>>(attn, act2, rs2, DIM);
  // GEMM2: BM=64, BN=64, full K. Grid 640 1-D: m = b/40, n = b%40.
  gemm_pipe<64, 64><<<640, 256, 0, stream>>>(
      act2, wodq, rs2, out, DIM, DIM, DIM, 0, 40, 40);
}